// Round 6
// baseline (469.494 us; speedup 1.0000x reference)
//
#include <hip/hip_runtime.h>

#define CACHELINE 64
#define THRESH 0.05f

// 64-wide float vector: a first-class SSA value in LLVM IR. All accesses below
// use compile-time-constant lane indices (template params), so the row lives in
// insertelement/extractelement chains on VGPRs -- no alloca, no scratch.
typedef float vfloat64 __attribute__((ext_vector_type(CACHELINE)));

// scanDown<IDX>: apply pair-updates for idx = IDX, IDX-1, ..., 0 (descending).
// Last write wins => the LOWEST matching idx determines r. 3 VALU per pair:
//   v_sub_f32, v_cmp_le_f32 (abs src modifier), v_cndmask_b32.
template<int IDX>
__device__ __forceinline__ float scanDown(const vfloat64& v, float xj, float r) {
    const float vi = v[IDX];                    // extractelement, literal index
    r = (fabsf(xj - vi) <= THRESH) ? vi : r;
    if constexpr (IDX > 0) {
        return scanDown<IDX - 1>(v, xj, r);
    } else {
        return r;
    }
}

// Column J: final[J] = final[idx*], idx* = min{ idx<J : |x_orig[J]-final[idx]| <= thr },
// else x_orig[J]. Columns processed ascending, so v[0..J-1] already hold finals.
template<int J>
__device__ __forceinline__ void scanAll(vfloat64& v) {
    if constexpr (J < CACHELINE) {
        const float xj = v[J];
        v[J] = scanDown<J - 1>(v, xj, xj);      // insertelement, literal index
        scanAll<J + 1>(v);
    }
}

__global__ __launch_bounds__(256) void cluster_kernel_v3(
        const float* __restrict__ x, float* __restrict__ out, long long nrows) {
    long long row = (long long)blockIdx.x * blockDim.x + threadIdx.x;
    if (row >= nrows) return;

    // One 256-byte vector load -> 16x global_load_dwordx4 (rows are 256B aligned).
    vfloat64 v = *reinterpret_cast<const vfloat64*>(x + row * CACHELINE);

    scanAll<1>(v);   // column 0 never changes

    *reinterpret_cast<vfloat64*>(out + row * CACHELINE) = v;
}

extern "C" void kernel_launch(void* const* d_in, const int* in_sizes, int n_in,
                              void* d_out, int out_size, void* d_ws, size_t ws_size,
                              hipStream_t stream) {
    const float* x = (const float*)d_in[0];
    float* out = (float*)d_out;
    long long n = in_sizes[0];
    long long nrows = n / CACHELINE;          // 1,048,576 for the bench shape
    int block = 256;
    long long grid = (nrows + block - 1) / block;  // 4096 blocks
    cluster_kernel_v3<<<(dim3)(unsigned)grid, block, 0, stream>>>(x, out, nrows);
}